// Round 13
// baseline (168.465 us; speedup 1.0000x reference)
//
#include <hip/hip_runtime.h>
#include <math.h>

#define LSEQ 2048
#define DM   1024
#define EDIM 2048
#define RNK  64
#define NS   16
#define DBCW 96          // R + 2N
#define LC   16          // scan chunk length
#define NCH  (LSEQ / LC) // 128 chunks
#define NSEG 8           // chunks per segment (tree scan)
#define NSEGS (NCH / NSEG) // 16 segments
#define SPLITK2 16       // G2 split-K factor
#define DLS_STRIDE 264   // LDS delta tile col stride (ushorts)

typedef __attribute__((ext_vector_type(4))) float f32x4;
typedef __attribute__((ext_vector_type(8))) __bf16 bf16x8;

__device__ __forceinline__ ushort f2bf(float f) {
    unsigned u = __float_as_uint(f);
    unsigned r = (u + 0x7fffu + ((u >> 16) & 1u)) >> 16;
    return (ushort)r;
}
__device__ __forceinline__ float bf2f(ushort u) {
    return __uint_as_float(((unsigned)u) << 16);
}

// ---------------------------------------------------------------------------
// Fused prep: casts x/in_proj_w/out_proj_w/x_proj_w/dt_proj_w to bf16,
// zero-pads x_proj_w rows 96..127. Ranges in f32-element units, 4/thread.
// ---------------------------------------------------------------------------
#define R0 2097152L               // x -> xbf
#define R1 (R0 + 4194304L)        // in_proj_w -> w1bf
#define R2 (R1 + 2097152L)        // out_proj_w -> w4bf
#define R3 (R2 + 196608L)         // x_proj_w -> xpw_pad rows 0..95
#define R4 (R3 + 131072L)         // dt_proj_w -> w3bf
#define R5 (R4 + 32768L)          // zero xpw_pad tail (rows 96..127)

__global__ __launch_bounds__(256) void prep_all(
    const float* __restrict__ x, const float* __restrict__ w1,
    const float* __restrict__ w4, const float* __restrict__ xpw,
    const float* __restrict__ w3,
    ushort* __restrict__ xbf, ushort* __restrict__ w1bf,
    ushort* __restrict__ w4bf, ushort* __restrict__ xpw_pad,
    ushort* __restrict__ w3bf)
{
    long idx4 = ((long)blockIdx.x * 256 + threadIdx.x) * 4;
    if (idx4 >= R5) return;
    if (idx4 >= R4) {   // zero xpw_pad tail: f32 view starting at ushort 196608
        long rel = idx4 - R4;
        float* p = (float*)(xpw_pad + 196608);
        *reinterpret_cast<float4*>(&p[rel]) = make_float4(0.f, 0.f, 0.f, 0.f);
        return;
    }
    const float* src; ushort* dst; long rel;
    if (idx4 < R0)      { src = x;   dst = xbf;     rel = idx4; }
    else if (idx4 < R1) { src = w1;  dst = w1bf;    rel = idx4 - R0; }
    else if (idx4 < R2) { src = w4;  dst = w4bf;    rel = idx4 - R1; }
    else if (idx4 < R3) { src = xpw; dst = xpw_pad; rel = idx4 - R2; }
    else                { src = w3;  dst = w3bf;    rel = idx4 - R3; }
    float4 v = *reinterpret_cast<const float4*>(&src[rel]);
    ushort4 o = make_ushort4(f2bf(v.x), f2bf(v.y), f2bf(v.z), f2bf(v.w));
    *reinterpret_cast<ushort4*>(&dst[rel]) = o;
}

// ---------------------------------------------------------------------------
// bf16 MFMA NT GEMM, 128x128 tile (G2). split-K via blocks_per_k; dual out.
// ---------------------------------------------------------------------------
__global__ __launch_bounds__(256) void gemm_nt_bf16(
    const ushort* __restrict__ A, int lda,
    const ushort* __restrict__ B, int ldb,
    float* __restrict__ C0, float* __restrict__ C1, int csplit, int ldc,
    long cplane, int klen, int grid_n, int blocks_per_k)
{
    __shared__ ushort As[128 * 32];
    __shared__ ushort Bs[128 * 32];
    const int tid = threadIdx.x;
    const int wave = tid >> 6;
    const int lane = tid & 63;
    const int kch = blockIdx.x / blocks_per_k;
    const int rem = blockIdx.x % blocks_per_k;
    const int bm = (rem / grid_n) * 128;
    const int bn = (rem % grid_n) * 128;
    const int wm = (wave & 1) * 64;
    const int wn = (wave >> 1) * 64;
    const int koff = kch * klen;
    C0 += (long)kch * cplane;

    f32x4 acc[4][4] = {};

    const int offT = tid * 16;
    const char* Ab = (const char*)A;
    const char* Bb = (const char*)B;
    char* AsB = (char*)As;
    char* BsB = (char*)Bs;

    for (int k0 = 0; k0 < klen; k0 += 32) {
        __syncthreads();
        #pragma unroll
        for (int r = 0; r < 2; ++r) {
            int off = r * 4096 + offT;
            int row = off >> 6;
            int kb = off & 63;
            __builtin_amdgcn_global_load_lds(
                (const __attribute__((address_space(1))) void*)
                    (Ab + ((long)(bm + row) * lda + koff + k0) * 2 + kb),
                (__attribute__((address_space(3))) void*)
                    (AsB + r * 4096 + wave * 1024), 16, 0, 0);
            __builtin_amdgcn_global_load_lds(
                (const __attribute__((address_space(1))) void*)
                    (Bb + ((long)(bn + row) * ldb + koff + k0) * 2 + kb),
                (__attribute__((address_space(3))) void*)
                    (BsB + r * 4096 + wave * 1024), 16, 0, 0);
        }
        __syncthreads();

        bf16x8 af[4], bfr[4];
        #pragma unroll
        for (int i = 0; i < 4; ++i) {
            int ar = wm + i * 16 + (lane & 15);
            af[i]  = *reinterpret_cast<const bf16x8*>(AsB + ar * 64 + (lane >> 4) * 16);
            int br = wn + i * 16 + (lane & 15);
            bfr[i] = *reinterpret_cast<const bf16x8*>(BsB + br * 64 + (lane >> 4) * 16);
        }
        #pragma unroll
        for (int i = 0; i < 4; ++i)
            #pragma unroll
            for (int j = 0; j < 4; ++j)
                acc[i][j] = __builtin_amdgcn_mfma_f32_16x16x32_bf16(
                    af[i], bfr[j], acc[i][j], 0, 0, 0);
    }

    #pragma unroll
    for (int i = 0; i < 4; ++i) {
        int row0 = bm + wm + i * 16 + (lane >> 4) * 4;
        #pragma unroll
        for (int j = 0; j < 4; ++j) {
            int col = bn + wn + j * 16 + (lane & 15);
            float* Cp;
            int cc;
            if (col < csplit) { Cp = C0; cc = col; }
            else              { Cp = C1; cc = col - csplit; }
            #pragma unroll
            for (int q = 0; q < 4; ++q)
                Cp[(long)(row0 + q) * ldc + cc] = acc[i][j][q];
        }
    }
}

// ---------------------------------------------------------------------------
// bf16 MFMA NT GEMM, 128x64 tile (G1/G4): 4 waves as 2x2 of 64x32, 12KB LDS.
// ---------------------------------------------------------------------------
__global__ __launch_bounds__(256) void gemm_nt_bf16_w64(
    const ushort* __restrict__ A, int lda,
    const ushort* __restrict__ B, int ldb,
    float* __restrict__ C0, float* __restrict__ C1, int csplit, int ldc,
    long cplane, int klen, int grid_n, int blocks_per_k)
{
    __shared__ ushort As[128 * 32];   // 8KB
    __shared__ ushort Bs[64 * 32];    // 4KB
    const int tid = threadIdx.x;
    const int wave = tid >> 6;
    const int lane = tid & 63;
    const int kch = blockIdx.x / blocks_per_k;
    const int rem = blockIdx.x % blocks_per_k;
    const int bm = (rem / grid_n) * 128;
    const int bn = (rem % grid_n) * 64;
    const int wm = (wave & 1) * 64;
    const int wn = (wave >> 1) * 32;
    const int koff = kch * klen;
    C0 += (long)kch * cplane;

    f32x4 acc[4][2] = {};

    const int offT = tid * 16;
    const char* Ab = (const char*)A;
    const char* Bb = (const char*)B;
    char* AsB = (char*)As;
    char* BsB = (char*)Bs;

    for (int k0 = 0; k0 < klen; k0 += 32) {
        __syncthreads();
        #pragma unroll
        for (int r = 0; r < 2; ++r) {
            int off = r * 4096 + offT;
            int row = off >> 6;
            int kb = off & 63;
            __builtin_amdgcn_global_load_lds(
                (const __attribute__((address_space(1))) void*)
                    (Ab + ((long)(bm + row) * lda + koff + k0) * 2 + kb),
                (__attribute__((address_space(3))) void*)
                    (AsB + r * 4096 + wave * 1024), 16, 0, 0);
        }
        {
            int row = offT >> 6;
            int kb = offT & 63;
            __builtin_amdgcn_global_load_lds(
                (const __attribute__((address_space(1))) void*)
                    (Bb + ((long)(bn + row) * ldb + koff + k0) * 2 + kb),
                (__attribute__((address_space(3))) void*)
                    (BsB + wave * 1024), 16, 0, 0);
        }
        __syncthreads();

        bf16x8 af[4], bfr[2];
        #pragma unroll
        for (int i = 0; i < 4; ++i) {
            int ar = wm + i * 16 + (lane & 15);
            af[i] = *reinterpret_cast<const bf16x8*>(AsB + ar * 64 + (lane >> 4) * 16);
        }
        #pragma unroll
        for (int j = 0; j < 2; ++j) {
            int br = wn + j * 16 + (lane & 15);
            bfr[j] = *reinterpret_cast<const bf16x8*>(BsB + br * 64 + (lane >> 4) * 16);
        }
        #pragma unroll
        for (int i = 0; i < 4; ++i)
            #pragma unroll
            for (int j = 0; j < 2; ++j)
                acc[i][j] = __builtin_amdgcn_mfma_f32_16x16x32_bf16(
                    af[i], bfr[j], acc[i][j], 0, 0, 0);
    }

    #pragma unroll
    for (int i = 0; i < 4; ++i) {
        int row0 = bm + wm + i * 16 + (lane >> 4) * 4;
        #pragma unroll
        for (int j = 0; j < 2; ++j) {
            int col = bn + wn + j * 16 + (lane & 15);
            float* Cp;
            int cc;
            if (col < csplit) { Cp = C0; cc = col; }
            else              { Cp = C1; cc = col - csplit; }
            #pragma unroll
            for (int q = 0; q < 4; ++q)
                Cp[(long)(row0 + q) * ldc + cc] = acc[i][j][q];
        }
    }
}

// G4 reduce: out = sum of 2 partial planes, float4
__global__ __launch_bounds__(256) void g4_reduce(
    const float* __restrict__ Gp, float* __restrict__ out)
{
    long i4 = ((long)blockIdx.x * 256 + threadIdx.x) * 4;
    float4 a = *reinterpret_cast<const float4*>(&Gp[i4]);
    float4 b = *reinterpret_cast<const float4*>(&Gp[2097152 + i4]);
    float4 o = make_float4(a.x + b.x, a.y + b.y, a.z + b.z, a.w + b.w);
    *reinterpret_cast<float4*>(&out[i4]) = o;
}

// G2 reduce: dbc = sum over SPLITK2 partial planes; also emit bf16 delta_r
__global__ __launch_bounds__(256) void gemm2_reduce(
    const float* __restrict__ Pb, float* __restrict__ dbc,
    ushort* __restrict__ dtr)
{
    int idx = blockIdx.x * 256 + threadIdx.x;   // 2048*96
    float s = 0.f;
    #pragma unroll
    for (int c = 0; c < SPLITK2; ++c) s += Pb[(long)c * LSEQ * DBCW + idx];
    dbc[idx] = s;
    int r = idx / DBCW;
    int c = idx - r * DBCW;
    if (c < RNK) dtr[r * RNK + c] = f2bf(s);
}

// ---------------------------------------------------------------------------
// Depthwise causal conv (K=4) + bias + SiLU. f32 in, bf16 out, 4 elems/thread.
// ---------------------------------------------------------------------------
__global__ __launch_bounds__(256) void conv_silu(
    const float* __restrict__ xr, const float* __restrict__ w,
    const float* __restrict__ b, ushort* __restrict__ xrc)
{
    int idx = blockIdx.x * 256 + threadIdx.x;   // l*512 + e4
    int l = idx >> 9;
    int e4 = (idx & 511) << 2;
    float4 zero = make_float4(0.f, 0.f, 0.f, 0.f);
    float4 r0 = (l >= 3) ? *reinterpret_cast<const float4*>(&xr[(long)(l - 3) * EDIM + e4]) : zero;
    float4 r1 = (l >= 2) ? *reinterpret_cast<const float4*>(&xr[(long)(l - 2) * EDIM + e4]) : zero;
    float4 r2 = (l >= 1) ? *reinterpret_cast<const float4*>(&xr[(long)(l - 1) * EDIM + e4]) : zero;
    float4 r3 = *reinterpret_cast<const float4*>(&xr[(long)l * EDIM + e4]);
    float4 bb = *reinterpret_cast<const float4*>(&b[e4]);
    float rr0[4] = {r0.x, r0.y, r0.z, r0.w};
    float rr1[4] = {r1.x, r1.y, r1.z, r1.w};
    float rr2[4] = {r2.x, r2.y, r2.z, r2.w};
    float rr3[4] = {r3.x, r3.y, r3.z, r3.w};
    float bbv[4] = {bb.x, bb.y, bb.z, bb.w};
    ushort o[4];
    #pragma unroll
    for (int j = 0; j < 4; ++j) {
        float4 wj = *reinterpret_cast<const float4*>(&w[(e4 + j) * 4]);
        float acc = bbv[j];
        acc = fmaf(wj.x, rr0[j], acc);
        acc = fmaf(wj.y, rr1[j], acc);
        acc = fmaf(wj.z, rr2[j], acc);
        acc = fmaf(wj.w, rr3[j], acc);
        o[j] = f2bf(acc / (1.f + __expf(-acc)));
    }
    *reinterpret_cast<ushort4*>(&xrc[(long)l * EDIM + e4]) =
        make_ushort4(o[0], o[1], o[2], o[3]);
}

// ---------------------------------------------------------------------------
// Fused delta tile: dls[16 t][256 e] = softplus(dtr[t]·w3[e] + bias[e]) bf16.
// 4 waves; wave w covers e-cols [w*64, w*64+64). One A-fragment (16 rows).
// ---------------------------------------------------------------------------
__device__ __forceinline__ void delta_tile_mfma(
    const ushort* __restrict__ dtr, const ushort* __restrict__ w3,
    const float* __restrict__ bias, ushort* dls, int t0, int eb, int tid)
{
    const int wave = tid >> 6;
    const int lane = tid & 63;
    f32x4 acc[4] = {};
    #pragma unroll
    for (int kk = 0; kk < 2; ++kk) {
        bf16x8 af, bfr[4];
        af = *reinterpret_cast<const bf16x8*>(
            &dtr[(long)(t0 + (lane & 15)) * RNK + kk * 32 + (lane >> 4) * 8]);
        #pragma unroll
        for (int j = 0; j < 4; ++j)
            bfr[j] = *reinterpret_cast<const bf16x8*>(
                &w3[(long)(eb + wave * 64 + j * 16 + (lane & 15)) * RNK + kk * 32 + (lane >> 4) * 8]);
        #pragma unroll
        for (int j = 0; j < 4; ++j)
            acc[j] = __builtin_amdgcn_mfma_f32_16x16x32_bf16(af, bfr[j], acc[j], 0, 0, 0);
    }
    #pragma unroll
    for (int j = 0; j < 4; ++j) {
        int el = wave * 64 + j * 16 + (lane & 15);
        float bv = bias[eb + el];
        #pragma unroll
        for (int q = 0; q < 4; ++q) {
            float v = acc[j][q] + bv;
            v = fmaxf(v, 0.f) + __logf(1.f + __expf(-fabsf(v)));
            dls[((lane >> 4) * 4 + q) * DLS_STRIDE + el] = f2bf(v);
        }
    }
}

// ---------------------------------------------------------------------------
// Selective scan. Phase A: block = (chunk c, 256-e slab). Delta tile in LDS
// via MFMA, then local scan; records decay product P and local final Hf.
// ---------------------------------------------------------------------------
__global__ __launch_bounds__(256) void scan_phaseA(
    const ushort* __restrict__ dtr, const ushort* __restrict__ w3,
    const float* __restrict__ bias,
    const ushort* __restrict__ xr, const float* __restrict__ dbc,
    const float* __restrict__ A_log,
    float* __restrict__ P, float* __restrict__ Hf)
{
    __shared__ ushort dls[LC * DLS_STRIDE];
    const int tid = threadIdx.x;
    const int blk = blockIdx.x;
    const int c = blk >> 3;
    const int eb = (blk & 7) * 256;
    const int e = eb + tid;
    const int t0 = c * LC;

    delta_tile_mfma(dtr, w3, bias, dls, t0, eb, tid);
    __syncthreads();

    float Aa[NS], h[NS], Pp[NS];
    #pragma unroll
    for (int n = 0; n < NS; ++n) {
        Aa[n] = -__expf(A_log[e * NS + n]);
        h[n] = 0.f;
        Pp[n] = 1.f;
    }
    for (int tt = 0; tt < LC; ++tt) {
        int t = t0 + tt;
        float d  = bf2f(dls[tt * DLS_STRIDE + tid]);
        float xv = bf2f(xr[(long)t * EDIM + e]);
        const float* bm = dbc + (long)t * DBCW + RNK;
        float dx = d * xv;
        #pragma unroll
        for (int n = 0; n < NS; ++n) {
            float a = __expf(d * Aa[n]);
            h[n] = fmaf(a, h[n], dx * bm[n]);
            Pp[n] *= a;
        }
    }
    #pragma unroll
    for (int n = 0; n < NS; ++n) {
        P [(long)(c * NS + n) * EDIM + e] = Pp[n];
        Hf[(long)(c * NS + n) * EDIM + e] = h[n];
    }
}

// Phase B1: per (e,n,segment): within-segment prefix over NSEG chunks.
__global__ __launch_bounds__(256) void scan_phaseB1(
    float* __restrict__ P, float* __restrict__ Hf,
    float* __restrict__ Sp, float* __restrict__ Sf)
{
    int gid = blockIdx.x * 256 + threadIdx.x;   // EDIM*NS*NSEGS
    int e = gid & (EDIM - 1);
    int n = (gid >> 11) & (NS - 1);
    int g = gid >> 15;                          // 0..NSEGS-1
    float h = 0.f, pp = 1.f;
    for (int c = g * NSEG; c < g * NSEG + NSEG; ++c) {
        long idx = (long)(c * NS + n) * EDIM + e;
        float p = P[idx];
        float f = Hf[idx];
        Hf[idx] = h;
        P[idx] = pp;
        h = fmaf(p, h, f);
        pp *= p;
    }
    long si = (long)(g * NS + n) * EDIM + e;
    Sp[si] = pp;
    Sf[si] = h;
}

// Phase B2: scan NSEGS segment summaries per (e,n); Sf[g] <- segment prefix.
__global__ __launch_bounds__(256) void scan_phaseB2(
    const float* __restrict__ Sp, float* __restrict__ Sf)
{
    int gid = blockIdx.x * 256 + threadIdx.x;   // EDIM*NS
    int e = gid & (EDIM - 1);
    int n = gid >> 11;
    float h = 0.f;
    for (int g = 0; g < NSEGS; ++g) {
        long idx = (long)(g * NS + n) * EDIM + e;
        float p = Sp[idx];
        float f = Sf[idx];
        Sf[idx] = h;
        h = fmaf(p, h, f);
    }
}

// Phase C: h_in(c) = P_within(c)*Sf(seg) + Hf_within(c); delta tile in LDS;
// local scan; u = (y + D*x) * silu(z) -> bf16
__global__ __launch_bounds__(256) void scan_phaseC(
    const ushort* __restrict__ dtr, const ushort* __restrict__ w3,
    const float* __restrict__ bias,
    const ushort* __restrict__ xr, const float* __restrict__ dbc,
    const float* __restrict__ A_log,
    const float* __restrict__ P, const float* __restrict__ Hf,
    const float* __restrict__ Sf, const float* __restrict__ Dp,
    const float* __restrict__ z, ushort* __restrict__ ubf)
{
    __shared__ ushort dls[LC * DLS_STRIDE];
    const int tid = threadIdx.x;
    const int blk = blockIdx.x;
    const int c = blk >> 3;
    const int eb = (blk & 7) * 256;
    const int e = eb + tid;
    const int g = c >> 3;
    const int t0 = c * LC;

    delta_tile_mfma(dtr, w3, bias, dls, t0, eb, tid);
    __syncthreads();

    float Aa[NS], h[NS];
    #pragma unroll
    for (int n = 0; n < NS; ++n) {
        Aa[n] = -__expf(A_log[e * NS + n]);
        long ci = (long)(c * NS + n) * EDIM + e;
        long si = (long)(g * NS + n) * EDIM + e;
        h[n] = fmaf(P[ci], Sf[si], Hf[ci]);
    }
    float dD = Dp[e];
    for (int tt = 0; tt < LC; ++tt) {
        int t = t0 + tt;
        float d  = bf2f(dls[tt * DLS_STRIDE + tid]);
        float xv = bf2f(xr[(long)t * EDIM + e]);
        const float* bm = dbc + (long)t * DBCW + RNK;
        const float* cm = dbc + (long)t * DBCW + RNK + NS;
        float dx = d * xv;
        float y = 0.f;
        #pragma unroll
        for (int n = 0; n < NS; ++n) {
            float a = __expf(d * Aa[n]);
            h[n] = fmaf(a, h[n], dx * bm[n]);
            y = fmaf(h[n], cm[n], y);
        }
        y = fmaf(dD, xv, y);
        float zv = z[(long)t * EDIM + e];
        float sz = zv / (1.f + __expf(-zv));
        ubf[(long)t * EDIM + e] = f2bf(y * sz);
    }
}

// ---------------------------------------------------------------------------
extern "C" void kernel_launch(void* const* d_in, const int* in_sizes, int n_in,
                              void* d_out, int out_size, void* d_ws, size_t ws_size,
                              hipStream_t stream) {
    const float* x         = (const float*)d_in[0];
    const float* in_proj_w = (const float*)d_in[1];
    const float* conv_w    = (const float*)d_in[2];
    const float* conv_b    = (const float*)d_in[3];
    const float* x_proj_w  = (const float*)d_in[4];
    const float* dt_proj_w = (const float*)d_in[5];
    const float* dt_proj_b = (const float*)d_in[6];
    const float* A_log     = (const float*)d_in[7];
    const float* Dp        = (const float*)d_in[8];
    const float* out_proj_w= (const float*)d_in[9];
    float* out = (float*)d_out;

    float* ws = (float*)d_ws;
    const long M1 = 1048576;
    // [0,1M): xbf ; [1M,3M): w1bf -> Pb [0,3M) -> ubf [0,2M)
    ushort* xbf     = (ushort*)ws;
    ushort* w1bf    = (ushort*)(ws + 1 * M1);
    float*  Pb      = ws;
    ushort* ubf     = (ushort*)ws;
    // [3M, 3.0625M): junk ; [3.25M,3.375M): xpw_pad ; [3.5M,4.5M): w4bf
    float*  junk    = ws + 3 * M1;
    ushort* xpw_pad = (ushort*)(ws + 3 * M1 + M1 / 4);
    ushort* w4bf    = (ushort*)(ws + 3 * M1 + M1 / 2);
    // [4.5M, 8.5M): xr_f32 (dead after conv) -> Hf [NCH][NS][EDIM] 4M f32
    //   (dead after scanC) -> Gp (2 planes, 4M f32)
    float*  xr_f32  = ws + 4 * M1 + M1 / 2;
    float*  Hf      = ws + 4 * M1 + M1 / 2;
    float*  Gp      = ws + 4 * M1 + M1 / 2;
    // [8.5M, 12.5M): z_f32
    float*  z_f32   = ws + 8 * M1 + M1 / 2;
    // [12.5M, 14.5M): xrcbf (4M ushort)
    ushort* xrcbf   = (ushort*)(ws + 12 * M1 + M1 / 2);
    // [14.5M, 18.5M): P [NCH][NS][EDIM] 4M f32
    float*  P       = ws + 14 * M1 + M1 / 2;
    // [18.5M, 19M): Sp (0.5M) ; [19M, 19.5M): Sf (0.5M)
    float*  Sp      = ws + 18 * M1 + M1 / 2;
    float*  Sf      = ws + 19 * M1;
    // [19.5M, ...): dbc (196608 f32), w3bf (131072 us), dtr_bf (131072 us)
    float*  dbc     = ws + 19 * M1 + M1 / 2;
    ushort* w3bf    = (ushort*)(ws + 19 * M1 + M1 / 2 + 196608);
    ushort* dtr_bf  = (ushort*)(ws + 19 * M1 + M1 / 2 + 196608 + 65536);

    dim3 blk(256);

    // prep: casts + x_proj_w pad
    prep_all<<<(R5 / 4 + 255) / 256, blk, 0, stream>>>(
        x, in_proj_w, out_proj_w, x_proj_w, dt_proj_w,
        xbf, w1bf, w4bf, xpw_pad, w3bf);

    // G1: [xr|z](f32 planes) = x @ in_proj_w^T  [2048,4096] k=1024
    gemm_nt_bf16_w64<<<1024, blk, 0, stream>>>(
        xbf, DM, w1bf, DM, xr_f32, z_f32, EDIM, EDIM, 0, DM, 64, 1024);

    // conv + silu: xr_f32 -> xrcbf (bf16); xr_f32 dead after this
    conv_silu<<<(LSEQ * EDIM) / 1024, blk, 0, stream>>>(xr_f32, conv_w, conv_b, xrcbf);

    // G2: Pb[kch] = xrcbf[:, kch*128:+128] @ xpw_pad^T  (MFMA, split-K x16)
    gemm_nt_bf16<<<SPLITK2 * 16, blk, 0, stream>>>(
        xrcbf, EDIM, xpw_pad, EDIM, Pb, junk, DBCW, DBCW,
        (long)LSEQ * DBCW, EDIM / SPLITK2, 1, 16);
    gemm2_reduce<<<(LSEQ * DBCW) / 256, blk, 0, stream>>>(Pb, dbc, dtr_bf);

    // scan (delta computed per-block in LDS via MFMA; LC=16 -> 1024 blocks)
    scan_phaseA<<<(NCH * EDIM) / 256, blk, 0, stream>>>(
        dtr_bf, w3bf, dt_proj_b, xrcbf, dbc, A_log, P, Hf);
    scan_phaseB1<<<(EDIM * NS * NSEGS) / 256, blk, 0, stream>>>(P, Hf, Sp, Sf);
    scan_phaseB2<<<(EDIM * NS) / 256, blk, 0, stream>>>(Sp, Sf);
    scan_phaseC<<<(NCH * EDIM) / 256, blk, 0, stream>>>(
        dtr_bf, w3bf, dt_proj_b, xrcbf, dbc, A_log, P, Hf, Sf, Dp, z_f32, ubf);

    // G4: Gp[kch] = u @ out_proj_w^T  [2048,1024] k=2048, split-K x2
    gemm_nt_bf16_w64<<<512, blk, 0, stream>>>(
        ubf, EDIM, w4bf, EDIM, Gp, junk, 1 << 30, DM,
        (long)LSEQ * DM, EDIM / 2, 16, 256);
    g4_reduce<<<(LSEQ * DM) / 1024, blk, 0, stream>>>(Gp, out);
}

// Round 14
// 159.327 us; speedup vs baseline: 1.0574x; 1.0574x over previous
//
#include <hip/hip_runtime.h>
#include <math.h>

#define LSEQ 2048
#define DM   1024
#define EDIM 2048
#define RNK  64
#define NS   16
#define DBCW 96          // R + 2N
#define LC   32          // scan chunk length
#define NCH  (LSEQ / LC) // 64 chunks
#define NSEG 8           // chunks per segment (tree scan)
#define NSEGS (NCH / NSEG) // 8 segments
#define SPLITK2 16       // G2 split-K factor
#define DLS_STRIDE 264   // LDS delta tile col stride (ushorts)

typedef __attribute__((ext_vector_type(4))) float f32x4;
typedef __attribute__((ext_vector_type(8))) __bf16 bf16x8;

__device__ __forceinline__ ushort f2bf(float f) {
    unsigned u = __float_as_uint(f);
    unsigned r = (u + 0x7fffu + ((u >> 16) & 1u)) >> 16;
    return (ushort)r;
}
__device__ __forceinline__ float bf2f(ushort u) {
    return __uint_as_float(((unsigned)u) << 16);
}

// ---------------------------------------------------------------------------
// Fused prep: casts x/in_proj_w/out_proj_w/x_proj_w/dt_proj_w to bf16,
// zero-pads x_proj_w rows 96..127. Ranges in f32-element units, 4/thread.
// ---------------------------------------------------------------------------
#define R0 2097152L               // x -> xbf
#define R1 (R0 + 4194304L)        // in_proj_w -> w1bf
#define R2 (R1 + 2097152L)        // out_proj_w -> w4bf
#define R3 (R2 + 196608L)         // x_proj_w -> xpw_pad rows 0..95
#define R4 (R3 + 131072L)         // dt_proj_w -> w3bf
#define R5 (R4 + 32768L)          // zero xpw_pad tail (rows 96..127)

__global__ __launch_bounds__(256) void prep_all(
    const float* __restrict__ x, const float* __restrict__ w1,
    const float* __restrict__ w4, const float* __restrict__ xpw,
    const float* __restrict__ w3,
    ushort* __restrict__ xbf, ushort* __restrict__ w1bf,
    ushort* __restrict__ w4bf, ushort* __restrict__ xpw_pad,
    ushort* __restrict__ w3bf)
{
    long idx4 = ((long)blockIdx.x * 256 + threadIdx.x) * 4;
    if (idx4 >= R5) return;
    if (idx4 >= R4) {   // zero xpw_pad tail: f32 view starting at ushort 196608
        long rel = idx4 - R4;
        float* p = (float*)(xpw_pad + 196608);
        *reinterpret_cast<float4*>(&p[rel]) = make_float4(0.f, 0.f, 0.f, 0.f);
        return;
    }
    const float* src; ushort* dst; long rel;
    if (idx4 < R0)      { src = x;   dst = xbf;     rel = idx4; }
    else if (idx4 < R1) { src = w1;  dst = w1bf;    rel = idx4 - R0; }
    else if (idx4 < R2) { src = w4;  dst = w4bf;    rel = idx4 - R1; }
    else if (idx4 < R3) { src = xpw; dst = xpw_pad; rel = idx4 - R2; }
    else                { src = w3;  dst = w3bf;    rel = idx4 - R3; }
    float4 v = *reinterpret_cast<const float4*>(&src[rel]);
    ushort4 o = make_ushort4(f2bf(v.x), f2bf(v.y), f2bf(v.z), f2bf(v.w));
    *reinterpret_cast<ushort4*>(&dst[rel]) = o;
}

// ---------------------------------------------------------------------------
// bf16 MFMA NT GEMM, 128x128 tile (G2). split-K via blocks_per_k; dual out.
// ---------------------------------------------------------------------------
__global__ __launch_bounds__(256) void gemm_nt_bf16(
    const ushort* __restrict__ A, int lda,
    const ushort* __restrict__ B, int ldb,
    float* __restrict__ C0, float* __restrict__ C1, int csplit, int ldc,
    long cplane, int klen, int grid_n, int blocks_per_k)
{
    __shared__ ushort As[128 * 32];
    __shared__ ushort Bs[128 * 32];
    const int tid = threadIdx.x;
    const int wave = tid >> 6;
    const int lane = tid & 63;
    const int kch = blockIdx.x / blocks_per_k;
    const int rem = blockIdx.x % blocks_per_k;
    const int bm = (rem / grid_n) * 128;
    const int bn = (rem % grid_n) * 128;
    const int wm = (wave & 1) * 64;
    const int wn = (wave >> 1) * 64;
    const int koff = kch * klen;
    C0 += (long)kch * cplane;

    f32x4 acc[4][4] = {};

    const int offT = tid * 16;
    const char* Ab = (const char*)A;
    const char* Bb = (const char*)B;
    char* AsB = (char*)As;
    char* BsB = (char*)Bs;

    for (int k0 = 0; k0 < klen; k0 += 32) {
        __syncthreads();
        #pragma unroll
        for (int r = 0; r < 2; ++r) {
            int off = r * 4096 + offT;
            int row = off >> 6;
            int kb = off & 63;
            __builtin_amdgcn_global_load_lds(
                (const __attribute__((address_space(1))) void*)
                    (Ab + ((long)(bm + row) * lda + koff + k0) * 2 + kb),
                (__attribute__((address_space(3))) void*)
                    (AsB + r * 4096 + wave * 1024), 16, 0, 0);
            __builtin_amdgcn_global_load_lds(
                (const __attribute__((address_space(1))) void*)
                    (Bb + ((long)(bn + row) * ldb + koff + k0) * 2 + kb),
                (__attribute__((address_space(3))) void*)
                    (BsB + r * 4096 + wave * 1024), 16, 0, 0);
        }
        __syncthreads();

        bf16x8 af[4], bfr[4];
        #pragma unroll
        for (int i = 0; i < 4; ++i) {
            int ar = wm + i * 16 + (lane & 15);
            af[i]  = *reinterpret_cast<const bf16x8*>(AsB + ar * 64 + (lane >> 4) * 16);
            int br = wn + i * 16 + (lane & 15);
            bfr[i] = *reinterpret_cast<const bf16x8*>(BsB + br * 64 + (lane >> 4) * 16);
        }
        #pragma unroll
        for (int i = 0; i < 4; ++i)
            #pragma unroll
            for (int j = 0; j < 4; ++j)
                acc[i][j] = __builtin_amdgcn_mfma_f32_16x16x32_bf16(
                    af[i], bfr[j], acc[i][j], 0, 0, 0);
    }

    #pragma unroll
    for (int i = 0; i < 4; ++i) {
        int row0 = bm + wm + i * 16 + (lane >> 4) * 4;
        #pragma unroll
        for (int j = 0; j < 4; ++j) {
            int col = bn + wn + j * 16 + (lane & 15);
            float* Cp;
            int cc;
            if (col < csplit) { Cp = C0; cc = col; }
            else              { Cp = C1; cc = col - csplit; }
            #pragma unroll
            for (int q = 0; q < 4; ++q)
                Cp[(long)(row0 + q) * ldc + cc] = acc[i][j][q];
        }
    }
}

// ---------------------------------------------------------------------------
// bf16 MFMA NT GEMM, 128x64 tile (G1/G4): 4 waves as 2x2 of 64x32, 12KB LDS.
// ---------------------------------------------------------------------------
__global__ __launch_bounds__(256) void gemm_nt_bf16_w64(
    const ushort* __restrict__ A, int lda,
    const ushort* __restrict__ B, int ldb,
    float* __restrict__ C0, float* __restrict__ C1, int csplit, int ldc,
    long cplane, int klen, int grid_n, int blocks_per_k)
{
    __shared__ ushort As[128 * 32];   // 8KB
    __shared__ ushort Bs[64 * 32];    // 4KB
    const int tid = threadIdx.x;
    const int wave = tid >> 6;
    const int lane = tid & 63;
    const int kch = blockIdx.x / blocks_per_k;
    const int rem = blockIdx.x % blocks_per_k;
    const int bm = (rem / grid_n) * 128;
    const int bn = (rem % grid_n) * 64;
    const int wm = (wave & 1) * 64;
    const int wn = (wave >> 1) * 32;
    const int koff = kch * klen;
    C0 += (long)kch * cplane;

    f32x4 acc[4][2] = {};

    const int offT = tid * 16;
    const char* Ab = (const char*)A;
    const char* Bb = (const char*)B;
    char* AsB = (char*)As;
    char* BsB = (char*)Bs;

    for (int k0 = 0; k0 < klen; k0 += 32) {
        __syncthreads();
        #pragma unroll
        for (int r = 0; r < 2; ++r) {
            int off = r * 4096 + offT;
            int row = off >> 6;
            int kb = off & 63;
            __builtin_amdgcn_global_load_lds(
                (const __attribute__((address_space(1))) void*)
                    (Ab + ((long)(bm + row) * lda + koff + k0) * 2 + kb),
                (__attribute__((address_space(3))) void*)
                    (AsB + r * 4096 + wave * 1024), 16, 0, 0);
        }
        {
            int row = offT >> 6;
            int kb = offT & 63;
            __builtin_amdgcn_global_load_lds(
                (const __attribute__((address_space(1))) void*)
                    (Bb + ((long)(bn + row) * ldb + koff + k0) * 2 + kb),
                (__attribute__((address_space(3))) void*)
                    (BsB + wave * 1024), 16, 0, 0);
        }
        __syncthreads();

        bf16x8 af[4], bfr[2];
        #pragma unroll
        for (int i = 0; i < 4; ++i) {
            int ar = wm + i * 16 + (lane & 15);
            af[i] = *reinterpret_cast<const bf16x8*>(AsB + ar * 64 + (lane >> 4) * 16);
        }
        #pragma unroll
        for (int j = 0; j < 2; ++j) {
            int br = wn + j * 16 + (lane & 15);
            bfr[j] = *reinterpret_cast<const bf16x8*>(BsB + br * 64 + (lane >> 4) * 16);
        }
        #pragma unroll
        for (int i = 0; i < 4; ++i)
            #pragma unroll
            for (int j = 0; j < 2; ++j)
                acc[i][j] = __builtin_amdgcn_mfma_f32_16x16x32_bf16(
                    af[i], bfr[j], acc[i][j], 0, 0, 0);
    }

    #pragma unroll
    for (int i = 0; i < 4; ++i) {
        int row0 = bm + wm + i * 16 + (lane >> 4) * 4;
        #pragma unroll
        for (int j = 0; j < 2; ++j) {
            int col = bn + wn + j * 16 + (lane & 15);
            float* Cp;
            int cc;
            if (col < csplit) { Cp = C0; cc = col; }
            else              { Cp = C1; cc = col - csplit; }
            #pragma unroll
            for (int q = 0; q < 4; ++q)
                Cp[(long)(row0 + q) * ldc + cc] = acc[i][j][q];
        }
    }
}

// G4 reduce: out = sum of 2 partial planes, float4
__global__ __launch_bounds__(256) void g4_reduce(
    const float* __restrict__ Gp, float* __restrict__ out)
{
    long i4 = ((long)blockIdx.x * 256 + threadIdx.x) * 4;
    float4 a = *reinterpret_cast<const float4*>(&Gp[i4]);
    float4 b = *reinterpret_cast<const float4*>(&Gp[2097152 + i4]);
    float4 o = make_float4(a.x + b.x, a.y + b.y, a.z + b.z, a.w + b.w);
    *reinterpret_cast<float4*>(&out[i4]) = o;
}

// G2 reduce: dbc = sum over SPLITK2 partial planes; also emit bf16 delta_r
__global__ __launch_bounds__(256) void gemm2_reduce(
    const float* __restrict__ Pb, float* __restrict__ dbc,
    ushort* __restrict__ dtr)
{
    int idx = blockIdx.x * 256 + threadIdx.x;   // 2048*96
    float s = 0.f;
    #pragma unroll
    for (int c = 0; c < SPLITK2; ++c) s += Pb[(long)c * LSEQ * DBCW + idx];
    dbc[idx] = s;
    int r = idx / DBCW;
    int c = idx - r * DBCW;
    if (c < RNK) dtr[r * RNK + c] = f2bf(s);
}

// ---------------------------------------------------------------------------
// Depthwise causal conv (K=4) + bias + SiLU. f32 in, bf16 out, 4 elems/thread.
// ---------------------------------------------------------------------------
__global__ __launch_bounds__(256) void conv_silu(
    const float* __restrict__ xr, const float* __restrict__ w,
    const float* __restrict__ b, ushort* __restrict__ xrc)
{
    int idx = blockIdx.x * 256 + threadIdx.x;   // l*512 + e4
    int l = idx >> 9;
    int e4 = (idx & 511) << 2;
    float4 zero = make_float4(0.f, 0.f, 0.f, 0.f);
    float4 r0 = (l >= 3) ? *reinterpret_cast<const float4*>(&xr[(long)(l - 3) * EDIM + e4]) : zero;
    float4 r1 = (l >= 2) ? *reinterpret_cast<const float4*>(&xr[(long)(l - 2) * EDIM + e4]) : zero;
    float4 r2 = (l >= 1) ? *reinterpret_cast<const float4*>(&xr[(long)(l - 1) * EDIM + e4]) : zero;
    float4 r3 = *reinterpret_cast<const float4*>(&xr[(long)l * EDIM + e4]);
    float4 bb = *reinterpret_cast<const float4*>(&b[e4]);
    float rr0[4] = {r0.x, r0.y, r0.z, r0.w};
    float rr1[4] = {r1.x, r1.y, r1.z, r1.w};
    float rr2[4] = {r2.x, r2.y, r2.z, r2.w};
    float rr3[4] = {r3.x, r3.y, r3.z, r3.w};
    float bbv[4] = {bb.x, bb.y, bb.z, bb.w};
    ushort o[4];
    #pragma unroll
    for (int j = 0; j < 4; ++j) {
        float4 wj = *reinterpret_cast<const float4*>(&w[(e4 + j) * 4]);
        float acc = bbv[j];
        acc = fmaf(wj.x, rr0[j], acc);
        acc = fmaf(wj.y, rr1[j], acc);
        acc = fmaf(wj.z, rr2[j], acc);
        acc = fmaf(wj.w, rr3[j], acc);
        o[j] = f2bf(acc / (1.f + __expf(-acc)));
    }
    *reinterpret_cast<ushort4*>(&xrc[(long)l * EDIM + e4]) =
        make_ushort4(o[0], o[1], o[2], o[3]);
}

// ---------------------------------------------------------------------------
// Fused delta tile: dls[32 t][256 e] = softplus(dtr[t]·w3[e] + bias[e]) bf16.
// 4 waves; wave w covers e-cols [w*64, w*64+64).
// ---------------------------------------------------------------------------
__device__ __forceinline__ void delta_tile_mfma(
    const ushort* __restrict__ dtr, const ushort* __restrict__ w3,
    const float* __restrict__ bias, ushort* dls, int t0, int eb, int tid)
{
    const int wave = tid >> 6;
    const int lane = tid & 63;
    f32x4 acc[2][4] = {};
    #pragma unroll
    for (int kk = 0; kk < 2; ++kk) {
        bf16x8 af[2], bfr[4];
        #pragma unroll
        for (int i = 0; i < 2; ++i)
            af[i] = *reinterpret_cast<const bf16x8*>(
                &dtr[(long)(t0 + i * 16 + (lane & 15)) * RNK + kk * 32 + (lane >> 4) * 8]);
        #pragma unroll
        for (int j = 0; j < 4; ++j)
            bfr[j] = *reinterpret_cast<const bf16x8*>(
                &w3[(long)(eb + wave * 64 + j * 16 + (lane & 15)) * RNK + kk * 32 + (lane >> 4) * 8]);
        #pragma unroll
        for (int i = 0; i < 2; ++i)
            #pragma unroll
            for (int j = 0; j < 4; ++j)
                acc[i][j] = __builtin_amdgcn_mfma_f32_16x16x32_bf16(
                    af[i], bfr[j], acc[i][j], 0, 0, 0);
    }
    #pragma unroll
    for (int i = 0; i < 2; ++i) {
        #pragma unroll
        for (int j = 0; j < 4; ++j) {
            int el = wave * 64 + j * 16 + (lane & 15);
            float bv = bias[eb + el];
            #pragma unroll
            for (int q = 0; q < 4; ++q) {
                float v = acc[i][j][q] + bv;
                v = fmaxf(v, 0.f) + __logf(1.f + __expf(-fabsf(v)));
                dls[(i * 16 + (lane >> 4) * 4 + q) * DLS_STRIDE + el] = f2bf(v);
            }
        }
    }
}

// ---------------------------------------------------------------------------
// Selective scan. Phase A: block = (chunk c, 256-e slab). Delta tile in LDS
// via MFMA; dbc B-slice staged in LDS (broadcast reads). Records P, Hf.
// ---------------------------------------------------------------------------
__global__ __launch_bounds__(256) void scan_phaseA(
    const ushort* __restrict__ dtr, const ushort* __restrict__ w3,
    const float* __restrict__ bias,
    const ushort* __restrict__ xr, const float* __restrict__ dbc,
    const float* __restrict__ A_log,
    float* __restrict__ P, float* __restrict__ Hf)
{
    __shared__ ushort dls[LC * DLS_STRIDE];
    __shared__ float dbcs[LC][16];      // B-slice: dbc[t][64..80]
    const int tid = threadIdx.x;
    const int blk = blockIdx.x;
    const int c = blk >> 3;
    const int eb = (blk & 7) * 256;
    const int e = eb + tid;
    const int t0 = c * LC;

    delta_tile_mfma(dtr, w3, bias, dls, t0, eb, tid);
    #pragma unroll
    for (int it = 0; it < 2; ++it) {    // 512 floats, 2 per thread
        int ix = tid + it * 256;
        dbcs[ix >> 4][ix & 15] = dbc[(long)(t0 + (ix >> 4)) * DBCW + RNK + (ix & 15)];
    }
    __syncthreads();

    float Aa[NS], h[NS], Pp[NS];
    #pragma unroll
    for (int n = 0; n < NS; ++n) {
        Aa[n] = -__expf(A_log[e * NS + n]);
        h[n] = 0.f;
        Pp[n] = 1.f;
    }
    for (int tt = 0; tt < LC; ++tt) {
        int t = t0 + tt;
        float d  = bf2f(dls[tt * DLS_STRIDE + tid]);
        float xv = bf2f(xr[(long)t * EDIM + e]);
        float bmv[16];
        #pragma unroll
        for (int q = 0; q < 4; ++q) {
            float4 vb = *reinterpret_cast<const float4*>(&dbcs[tt][q * 4]);
            bmv[q * 4 + 0] = vb.x; bmv[q * 4 + 1] = vb.y;
            bmv[q * 4 + 2] = vb.z; bmv[q * 4 + 3] = vb.w;
        }
        float dx = d * xv;
        #pragma unroll
        for (int n = 0; n < NS; ++n) {
            float a = __expf(d * Aa[n]);
            h[n] = fmaf(a, h[n], dx * bmv[n]);
            Pp[n] *= a;
        }
    }
    #pragma unroll
    for (int n = 0; n < NS; ++n) {
        P [(long)(c * NS + n) * EDIM + e] = Pp[n];
        Hf[(long)(c * NS + n) * EDIM + e] = h[n];
    }
}

// Phase B1: per (e,n,segment): within-segment prefix over NSEG chunks.
__global__ __launch_bounds__(256) void scan_phaseB1(
    float* __restrict__ P, float* __restrict__ Hf,
    float* __restrict__ Sp, float* __restrict__ Sf)
{
    int gid = blockIdx.x * 256 + threadIdx.x;   // EDIM*NS*NSEGS
    int e = gid & (EDIM - 1);
    int n = (gid >> 11) & (NS - 1);
    int g = gid >> 15;
    float h = 0.f, pp = 1.f;
    for (int c = g * NSEG; c < g * NSEG + NSEG; ++c) {
        long idx = (long)(c * NS + n) * EDIM + e;
        float p = P[idx];
        float f = Hf[idx];
        Hf[idx] = h;
        P[idx] = pp;
        h = fmaf(p, h, f);
        pp *= p;
    }
    long si = (long)(g * NS + n) * EDIM + e;
    Sp[si] = pp;
    Sf[si] = h;
}

// Phase B2: scan NSEGS segment summaries per (e,n); Sf[g] <- segment prefix.
__global__ __launch_bounds__(256) void scan_phaseB2(
    const float* __restrict__ Sp, float* __restrict__ Sf)
{
    int gid = blockIdx.x * 256 + threadIdx.x;   // EDIM*NS
    int e = gid & (EDIM - 1);
    int n = gid >> 11;
    float h = 0.f;
    for (int g = 0; g < NSEGS; ++g) {
        long idx = (long)(g * NS + n) * EDIM + e;
        float p = Sp[idx];
        float f = Sf[idx];
        Sf[idx] = h;
        h = fmaf(p, h, f);
    }
}

// Phase C: h_in(c) = P_within(c)*Sf(seg) + Hf_within(c); delta tile in LDS;
// dbc B+C slices staged in LDS; local scan; u = (y + D*x)*silu(z) -> bf16
__global__ __launch_bounds__(256) void scan_phaseC(
    const ushort* __restrict__ dtr, const ushort* __restrict__ w3,
    const float* __restrict__ bias,
    const ushort* __restrict__ xr, const float* __restrict__ dbc,
    const float* __restrict__ A_log,
    const float* __restrict__ P, const float* __restrict__ Hf,
    const float* __restrict__ Sf, const float* __restrict__ Dp,
    const float* __restrict__ z, ushort* __restrict__ ubf)
{
    __shared__ ushort dls[LC * DLS_STRIDE];
    __shared__ float dbcs[LC][32];      // B+C slices: dbc[t][64..96]
    const int tid = threadIdx.x;
    const int blk = blockIdx.x;
    const int c = blk >> 3;
    const int eb = (blk & 7) * 256;
    const int e = eb + tid;
    const int g = c >> 3;
    const int t0 = c * LC;

    delta_tile_mfma(dtr, w3, bias, dls, t0, eb, tid);
    #pragma unroll
    for (int it = 0; it < 4; ++it) {    // 1024 floats, 4 per thread
        int ix = tid + it * 256;
        dbcs[ix >> 5][ix & 31] = dbc[(long)(t0 + (ix >> 5)) * DBCW + RNK + (ix & 31)];
    }
    __syncthreads();

    float Aa[NS], h[NS];
    #pragma unroll
    for (int n = 0; n < NS; ++n) {
        Aa[n] = -__expf(A_log[e * NS + n]);
        long ci = (long)(c * NS + n) * EDIM + e;
        long si = (long)(g * NS + n) * EDIM + e;
        h[n] = fmaf(P[ci], Sf[si], Hf[ci]);
    }
    float dD = Dp[e];
    for (int tt = 0; tt < LC; ++tt) {
        int t = t0 + tt;
        float d  = bf2f(dls[tt * DLS_STRIDE + tid]);
        float xv = bf2f(xr[(long)t * EDIM + e]);
        float bmv[16], cmv[16];
        #pragma unroll
        for (int q = 0; q < 4; ++q) {
            float4 vb = *reinterpret_cast<const float4*>(&dbcs[tt][q * 4]);
            float4 vc = *reinterpret_cast<const float4*>(&dbcs[tt][16 + q * 4]);
            bmv[q * 4 + 0] = vb.x; bmv[q * 4 + 1] = vb.y;
            bmv[q * 4 + 2] = vb.z; bmv[q * 4 + 3] = vb.w;
            cmv[q * 4 + 0] = vc.x; cmv[q * 4 + 1] = vc.y;
            cmv[q * 4 + 2] = vc.z; cmv[q * 4 + 3] = vc.w;
        }
        float dx = d * xv;
        float y = 0.f;
        #pragma unroll
        for (int n = 0; n < NS; ++n) {
            float a = __expf(d * Aa[n]);
            h[n] = fmaf(a, h[n], dx * bmv[n]);
            y = fmaf(h[n], cmv[n], y);
        }
        y = fmaf(dD, xv, y);
        float zv = z[(long)t * EDIM + e];
        float sz = zv / (1.f + __expf(-zv));
        ubf[(long)t * EDIM + e] = f2bf(y * sz);
    }
}

// ---------------------------------------------------------------------------
extern "C" void kernel_launch(void* const* d_in, const int* in_sizes, int n_in,
                              void* d_out, int out_size, void* d_ws, size_t ws_size,
                              hipStream_t stream) {
    const float* x         = (const float*)d_in[0];
    const float* in_proj_w = (const float*)d_in[1];
    const float* conv_w    = (const float*)d_in[2];
    const float* conv_b    = (const float*)d_in[3];
    const float* x_proj_w  = (const float*)d_in[4];
    const float* dt_proj_w = (const float*)d_in[5];
    const float* dt_proj_b = (const float*)d_in[6];
    const float* A_log     = (const float*)d_in[7];
    const float* Dp        = (const float*)d_in[8];
    const float* out_proj_w= (const float*)d_in[9];
    float* out = (float*)d_out;

    float* ws = (float*)d_ws;
    const long M1 = 1048576;
    // [0,1M): xbf ; [1M,3M): w1bf -> Pb [0,3M) -> ubf [0,2M)
    ushort* xbf     = (ushort*)ws;
    ushort* w1bf    = (ushort*)(ws + 1 * M1);
    float*  Pb      = ws;
    ushort* ubf     = (ushort*)ws;
    // [3M, 3.0625M): junk ; [3.25M,3.375M): xpw_pad ; [3.5M,4.5M): w4bf
    float*  junk    = ws + 3 * M1;
    ushort* xpw_pad = (ushort*)(ws + 3 * M1 + M1 / 4);
    ushort* w4bf    = (ushort*)(ws + 3 * M1 + M1 / 2);
    // [4.5M, 8.5M): xr_f32 (dead after conv) -> Hf (2M f32) ->
    //   after scanC Gp (2 planes, 4M f32)
    float*  xr_f32  = ws + 4 * M1 + M1 / 2;
    float*  Hf      = ws + 4 * M1 + M1 / 2;
    float*  Gp      = ws + 4 * M1 + M1 / 2;
    // [8.5M, 12.5M): z_f32
    float*  z_f32   = ws + 8 * M1 + M1 / 2;
    // [12.5M, 14.5M): xrcbf (4M ushort)
    ushort* xrcbf   = (ushort*)(ws + 12 * M1 + M1 / 2);
    // [14.5M, 16.5M): P (2M f32)
    float*  P       = ws + 14 * M1 + M1 / 2;
    // [18.5M, 19M): Sp ; [19M, 19.5M): Sf
    float*  Sp      = ws + 18 * M1 + M1 / 2;
    float*  Sf      = ws + 19 * M1;
    // [19.5M, ...): dbc (196608 f32), w3bf (131072 us), dtr_bf (131072 us)
    float*  dbc     = ws + 19 * M1 + M1 / 2;
    ushort* w3bf    = (ushort*)(ws + 19 * M1 + M1 / 2 + 196608);
    ushort* dtr_bf  = (ushort*)(ws + 19 * M1 + M1 / 2 + 196608 + 65536);

    dim3 blk(256);

    // prep: casts + x_proj_w pad
    prep_all<<<(R5 / 4 + 255) / 256, blk, 0, stream>>>(
        x, in_proj_w, out_proj_w, x_proj_w, dt_proj_w,
        xbf, w1bf, w4bf, xpw_pad, w3bf);

    // G1: [xr|z](f32 planes) = x @ in_proj_w^T  [2048,4096] k=1024
    gemm_nt_bf16_w64<<<1024, blk, 0, stream>>>(
        xbf, DM, w1bf, DM, xr_f32, z_f32, EDIM, EDIM, 0, DM, 64, 1024);

    // conv + silu: xr_f32 -> xrcbf (bf16); xr_f32 dead after this
    conv_silu<<<(LSEQ * EDIM) / 1024, blk, 0, stream>>>(xr_f32, conv_w, conv_b, xrcbf);

    // G2: Pb[kch] = xrcbf[:, kch*128:+128] @ xpw_pad^T  (MFMA, split-K x16)
    gemm_nt_bf16<<<SPLITK2 * 16, blk, 0, stream>>>(
        xrcbf, EDIM, xpw_pad, EDIM, Pb, junk, DBCW, DBCW,
        (long)LSEQ * DBCW, EDIM / SPLITK2, 1, 16);
    gemm2_reduce<<<(LSEQ * DBCW) / 256, blk, 0, stream>>>(Pb, dbc, dtr_bf);

    // scan (delta in LDS via MFMA; dbc slices staged in LDS)
    scan_phaseA<<<(NCH * EDIM) / 256, blk, 0, stream>>>(
        dtr_bf, w3bf, dt_proj_b, xrcbf, dbc, A_log, P, Hf);
    scan_phaseB1<<<(EDIM * NS * NSEGS) / 256, blk, 0, stream>>>(P, Hf, Sp, Sf);
    scan_phaseB2<<<(EDIM * NS) / 256, blk, 0, stream>>>(Sp, Sf);
    scan_phaseC<<<(NCH * EDIM) / 256, blk, 0, stream>>>(
        dtr_bf, w3bf, dt_proj_b, xrcbf, dbc, A_log, P, Hf, Sf, Dp, z_f32, ubf);

    // G4: Gp[kch] = u @ out_proj_w^T  [2048,1024] k=2048, split-K x2
    gemm_nt_bf16_w64<<<512, blk, 0, stream>>>(
        ubf, EDIM, w4bf, EDIM, Gp, junk, 1 << 30, DM,
        (long)LSEQ * DM, EDIM / 2, 16, 256);
    g4_reduce<<<(LSEQ * DM) / 1024, blk, 0, stream>>>(Gp, out);
}